// Round 1
// baseline (645.514 us; speedup 1.0000x reference)
//
#include <hip/hip_runtime.h>
#include <hip/hip_bf16.h>
#include <stdint.h>

// Fused gather + (ep-eq)^2 + MLP(256->256->256->1) for MI355X (gfx950).
//
// Design:
//  - Block = 512 threads (8 waves), tile = 128 queries.
//  - Phase 0: one wave loads one embedding row (64 lanes x float4 = 1 KB),
//    diff^2 in fp32, bf16 into XOR-swizzled LDS A-tile (64 KB).
//  - GEMM1/GEMM2: v_mfma_f32_16x16x32_bf16, wave tile 64x64 (4x4 MFMA tiles).
//    B-fragments are REGISTER-resident (loaded from a frag-packed bf16 copy
//    of W1/W2 in d_ws) -> barrier-free K-loop, only A comes from LDS.
//  - GEMM1 epilogue: +b1, relu, bf16 -> swizzled LDS H (64 KB).
//  - GEMM2 epilogue fuses the w3 dot: partials * w3[col], shfl_xor reduce
//    across the 16 lanes of each quad, cross-wave sum in 2 KB LDS, +b3.
// LDS total = 130 KB (1 block/CU, 2 waves/SIMD).

#define D 256
#define MT 128
#define THREADS 512

typedef __attribute__((ext_vector_type(8))) short short8;
typedef __attribute__((ext_vector_type(4))) float f32x4;

// bf16 round-to-nearest-even, header-type independent
__device__ __forceinline__ unsigned short f2bf(float f) {
    unsigned int u = __float_as_uint(f);
    unsigned int r = (u + 0x7FFFu + ((u >> 16) & 1u)) >> 16;
    return (unsigned short)r;
}

// ---------------- weight packing ----------------
// Pack W (row-major fp32 [K=256][N=256]) into bf16 B-fragments for
// v_mfma_f32_16x16x32_bf16. Fragment (nt, ks): lane L holds
//   B[k = ks*32 + (L>>4)*8 + j][n = nt*16 + (L&15)], j = 0..7
// stored contiguously at elem offset (((nt*8)+ks)*64 + L)*8.
__global__ void pack_w_kernel(const float* __restrict__ w1,
                              const float* __restrict__ w2,
                              unsigned short* __restrict__ out) {
    int tid = blockIdx.x * blockDim.x + threadIdx.x;   // 0..16383
    int mat = tid >> 13;                                // 0: w1, 1: w2
    const float* W = mat ? w2 : w1;
    unsigned short* o = out + mat * 65536;
    int rem  = tid & 8191;
    int nt   = rem >> 9;          // 0..15
    int ks   = (rem >> 6) & 7;    // 0..7
    int lane = rem & 63;
    int kbase = ks * 32 + (lane >> 4) * 8;
    int n     = nt * 16 + (lane & 15);
    short8 v;
#pragma unroll
    for (int j = 0; j < 8; ++j)
        v[j] = (short)f2bf(W[(kbase + j) * 256 + n]);
    *reinterpret_cast<short8*>(o + (((nt * 8) + ks) * 64 + lane) * 8) = v;
}

// ---------------- fused main kernel ----------------
__launch_bounds__(THREADS, 2)
__global__ void fused_kernel(const int* __restrict__ pv,
                             const int* __restrict__ qv,
                             const float* __restrict__ emb,
                             const float* __restrict__ b1,
                             const float* __restrict__ b2,
                             const float* __restrict__ w3,
                             const float* __restrict__ b3,
                             const unsigned short* __restrict__ wpack,
                             float* __restrict__ out,
                             int M) {
    // XOR-swizzled tiles: row stride 512 B (256 bf16), 16 B unit u at
    // physical unit (u ^ (row & 31)) -> conflict-free ds_read_b128 frags.
    __shared__ unsigned char lds_a[MT * 512];
    __shared__ unsigned char lds_h[MT * 512];
    __shared__ float lds_part[4][MT];

    const int tid  = threadIdx.x;
    const int lane = tid & 63;
    const int wave = tid >> 6;              // 0..7
    const int base = blockIdx.x * MT;

    // ---- phase 0: gather + squared diff -> bf16 -> lds_a ----
#pragma unroll
    for (int rr = 0; rr < 16; ++rr) {
        int r  = wave * 16 + rr;
        int gi = base + r;
        int pi = 0, qi = 0;
        if (gi < M) { pi = pv[gi]; qi = qv[gi]; }
        const float4* ep = reinterpret_cast<const float4*>(emb + (size_t)pi * D);
        const float4* eq = reinterpret_cast<const float4*>(emb + (size_t)qi * D);
        float4 a = ep[lane];
        float4 b = eq[lane];
        float d0 = a.x - b.x, d1 = a.y - b.y, d2 = a.z - b.z, d3 = a.w - b.w;
        unsigned int lo = (unsigned int)f2bf(d0 * d0) | ((unsigned int)f2bf(d1 * d1) << 16);
        unsigned int hi = (unsigned int)f2bf(d2 * d2) | ((unsigned int)f2bf(d3 * d3) << 16);
        unsigned int unit = (unsigned int)(lane >> 1) ^ (unsigned int)(r & 31);
        unsigned int addr = (unsigned int)r * 512u + (unit << 4) + (unsigned int)(lane & 1) * 8u;
        *reinterpret_cast<uint2*>(&lds_a[addr]) = make_uint2(lo, hi);
    }
    __syncthreads();

    const int wm    = wave & 1;     // m half:   rows  64*wm .. +64
    const int wn    = wave >> 1;    // n quarter: cols 64*wn .. +64
    const int mbase = wm * 64;
    const int nbase = wn * 64;
    const int l15   = lane & 15;
    const int quad  = lane >> 4;

    const short8* wp1 = reinterpret_cast<const short8*>(wpack);
    const short8* wp2 = reinterpret_cast<const short8*>(wpack + 65536);

    f32x4 acc[4][4];
    short8 bfr[4][8];   // [ct][ks] register-resident B fragments

    // ================= GEMM1: h1 = relu(A @ W1 + b1) =================
#pragma unroll
    for (int ct = 0; ct < 4; ++ct) {
        int ntg = (nbase >> 4) + ct;
#pragma unroll
        for (int ks = 0; ks < 8; ++ks)
            bfr[ct][ks] = wp1[((ntg * 8) + ks) * 64 + lane];
    }
#pragma unroll
    for (int mt = 0; mt < 4; ++mt)
#pragma unroll
        for (int ct = 0; ct < 4; ++ct)
            acc[mt][ct] = (f32x4){0.f, 0.f, 0.f, 0.f};

#pragma unroll
    for (int ks = 0; ks < 8; ++ks) {
        short8 af[4];
#pragma unroll
        for (int mt = 0; mt < 4; ++mt) {
            int r = mbase + mt * 16 + l15;
            unsigned int unit = (unsigned int)(ks * 4 + quad) ^ (unsigned int)(r & 31);
            af[mt] = *reinterpret_cast<const short8*>(&lds_a[(unsigned int)r * 512u + (unit << 4)]);
        }
#pragma unroll
        for (int mt = 0; mt < 4; ++mt)
#pragma unroll
            for (int ct = 0; ct < 4; ++ct)
                acc[mt][ct] = __builtin_amdgcn_mfma_f32_16x16x32_bf16(
                    af[mt], bfr[ct][ks], acc[mt][ct], 0, 0, 0);
    }

    // epilogue 1: +b1, relu, bf16 -> lds_h (C/D layout: col=lane&15, row=quad*4+reg)
#pragma unroll
    for (int ct = 0; ct < 4; ++ct) {
        int c = nbase + ct * 16 + l15;
        float bias = b1[c];
#pragma unroll
        for (int mt = 0; mt < 4; ++mt) {
#pragma unroll
            for (int j = 0; j < 4; ++j) {
                float v = acc[mt][ct][j] + bias;
                v = fmaxf(v, 0.f);
                int r = mbase + mt * 16 + quad * 4 + j;
                unsigned int unit = (unsigned int)(c >> 3) ^ (unsigned int)(r & 31);
                unsigned int addr = (unsigned int)r * 512u + (unit << 4) + (unsigned int)(c & 7) * 2u;
                *reinterpret_cast<unsigned short*>(&lds_h[addr]) = f2bf(v);
            }
        }
    }
    __syncthreads();

    // ================= GEMM2: h2 = relu(H @ W2 + b2), fused w3 dot =================
#pragma unroll
    for (int ct = 0; ct < 4; ++ct) {
        int ntg = (nbase >> 4) + ct;
#pragma unroll
        for (int ks = 0; ks < 8; ++ks)
            bfr[ct][ks] = wp2[((ntg * 8) + ks) * 64 + lane];
    }
#pragma unroll
    for (int mt = 0; mt < 4; ++mt)
#pragma unroll
        for (int ct = 0; ct < 4; ++ct)
            acc[mt][ct] = (f32x4){0.f, 0.f, 0.f, 0.f};

#pragma unroll
    for (int ks = 0; ks < 8; ++ks) {
        short8 af[4];
#pragma unroll
        for (int mt = 0; mt < 4; ++mt) {
            int r = mbase + mt * 16 + l15;
            unsigned int unit = (unsigned int)(ks * 4 + quad) ^ (unsigned int)(r & 31);
            af[mt] = *reinterpret_cast<const short8*>(&lds_h[(unsigned int)r * 512u + (unit << 4)]);
        }
#pragma unroll
        for (int mt = 0; mt < 4; ++mt)
#pragma unroll
            for (int ct = 0; ct < 4; ++ct)
                acc[mt][ct] = __builtin_amdgcn_mfma_f32_16x16x32_bf16(
                    af[mt], bfr[ct][ks], acc[mt][ct], 0, 0, 0);
    }

    float part[4][4];
#pragma unroll
    for (int mt = 0; mt < 4; ++mt)
#pragma unroll
        for (int j = 0; j < 4; ++j)
            part[mt][j] = 0.f;

#pragma unroll
    for (int ct = 0; ct < 4; ++ct) {
        int c = nbase + ct * 16 + l15;
        float bias = b2[c];
        float w3v  = w3[c];
#pragma unroll
        for (int mt = 0; mt < 4; ++mt)
#pragma unroll
            for (int j = 0; j < 4; ++j) {
                float v = acc[mt][ct][j] + bias;
                v = fmaxf(v, 0.f);
                part[mt][j] += v * w3v;
            }
    }

    // reduce across the 16 lanes of each quad (same rows, different cols)
#pragma unroll
    for (int msk = 8; msk >= 1; msk >>= 1)
#pragma unroll
        for (int mt = 0; mt < 4; ++mt)
#pragma unroll
            for (int j = 0; j < 4; ++j)
                part[mt][j] += __shfl_xor(part[mt][j], msk, 64);

    if (l15 == 0) {
#pragma unroll
        for (int mt = 0; mt < 4; ++mt)
#pragma unroll
            for (int j = 0; j < 4; ++j) {
                int r = mbase + mt * 16 + quad * 4 + j;
                lds_part[wn][r] = part[mt][j];
            }
    }
    __syncthreads();

    // cross-wave (n-quarter) sum + b3 + store
    if (tid < MT) {
        int gi = base + tid;
        if (gi < M) {
            float s = lds_part[0][tid] + lds_part[1][tid] +
                      lds_part[2][tid] + lds_part[3][tid] + b3[0];
            out[gi] = s;
        }
    }
}

extern "C" void kernel_launch(void* const* d_in, const int* in_sizes, int n_in,
                              void* d_out, int out_size, void* d_ws, size_t ws_size,
                              hipStream_t stream) {
    const int*   pv  = (const int*)d_in[0];
    const int*   qv  = (const int*)d_in[1];
    const float* emb = (const float*)d_in[2];
    const float* w1  = (const float*)d_in[3];
    const float* b1  = (const float*)d_in[4];
    const float* w2  = (const float*)d_in[5];
    const float* b2  = (const float*)d_in[6];
    const float* w3  = (const float*)d_in[7];
    const float* b3  = (const float*)d_in[8];
    float* out = (float*)d_out;
    const int M = in_sizes[0];

    unsigned short* wpack = (unsigned short*)d_ws;   // 2 * 65536 bf16 = 256 KB

    // pack W1/W2 into MFMA B-fragment order (runs every launch: d_ws is re-poisoned)
    pack_w_kernel<<<32, 512, 0, stream>>>(w1, w2, wpack);

    int nblk = (M + MT - 1) / MT;
    fused_kernel<<<nblk, THREADS, 0, stream>>>(pv, qv, emb, b1, b2, w3, b3,
                                               wpack, out, M);
}

// Round 2
// 603.515 us; speedup vs baseline: 1.0696x; 1.0696x over previous
//
#include <hip/hip_runtime.h>
#include <hip/hip_bf16.h>
#include <stdint.h>

// Fused gather + (ep-eq)^2 + MLP(256->256->256->1) for MI355X (gfx950).
//
// Round 2 changes vs round 1 (452 us, Occ 22.7%, MfmaUtil 12%, FETCH 507 MB):
//  - LDS: H tile reuses the A tile buffer (extra barrier after GEMM1 K-loop).
//    130 KB -> 66 KB => 2 blocks/CU, 16 waves/CU (latency hiding x2).
//  - Embedding table pre-converted to bf16 in d_ws (102.4 MB, L3-resident;
//    fp32's 205 MB thrashed the 256 MB L3). Gather bytes halve: 1.02 GB ->
//    512 MB logical. Guarded by ws_size with fp32 fallback (launch-constant
//    branch, graph-capture safe).
//  - Gather: 2 rows per wave-iteration (half-wave per row, 16 B/lane loads).

#define D 256
#define MT 128
#define THREADS 512

typedef __attribute__((ext_vector_type(8))) short short8;
typedef __attribute__((ext_vector_type(4))) float f32x4;

// bf16 round-to-nearest-even
__device__ __forceinline__ unsigned short f2bf(float f) {
    unsigned int u = __float_as_uint(f);
    unsigned int r = (u + 0x7FFFu + ((u >> 16) & 1u)) >> 16;
    return (unsigned short)r;
}
__device__ __forceinline__ float bflo(unsigned int u) { return __uint_as_float(u << 16); }
__device__ __forceinline__ float bfhi(unsigned int u) { return __uint_as_float(u & 0xFFFF0000u); }

// (p-q)^2 for a packed pair of bf16, result packed bf16
__device__ __forceinline__ unsigned int sqdiff2(unsigned int p, unsigned int q) {
    float d0 = bflo(p) - bflo(q);
    float d1 = bfhi(p) - bfhi(q);
    return (unsigned int)f2bf(d0 * d0) | ((unsigned int)f2bf(d1 * d1) << 16);
}

// ---------------- embedding fp32 -> bf16 table ----------------
__global__ void conv_emb_kernel(const float* __restrict__ in,
                                unsigned short* __restrict__ out, int nchunks) {
    int i = blockIdx.x * blockDim.x + threadIdx.x;   // one 8-elem chunk per thread
    if (i >= nchunks) return;
    const float4* p = reinterpret_cast<const float4*>(in) + 2 * (size_t)i;
    float4 a = p[0], b = p[1];
    uint4 o;
    o.x = (unsigned int)f2bf(a.x) | ((unsigned int)f2bf(a.y) << 16);
    o.y = (unsigned int)f2bf(a.z) | ((unsigned int)f2bf(a.w) << 16);
    o.z = (unsigned int)f2bf(b.x) | ((unsigned int)f2bf(b.y) << 16);
    o.w = (unsigned int)f2bf(b.z) | ((unsigned int)f2bf(b.w) << 16);
    reinterpret_cast<uint4*>(out)[i] = o;
}

// ---------------- weight packing ----------------
// Pack W (row-major fp32 [K=256][N=256]) into bf16 B-fragments for
// v_mfma_f32_16x16x32_bf16. Fragment (nt, ks): lane L holds
//   B[k = ks*32 + (L>>4)*8 + j][n = nt*16 + (L&15)], j = 0..7
__global__ void pack_w_kernel(const float* __restrict__ w1,
                              const float* __restrict__ w2,
                              unsigned short* __restrict__ out) {
    int tid = blockIdx.x * blockDim.x + threadIdx.x;   // 0..16383
    int mat = tid >> 13;
    const float* W = mat ? w2 : w1;
    unsigned short* o = out + mat * 65536;
    int rem  = tid & 8191;
    int nt   = rem >> 9;
    int ks   = (rem >> 6) & 7;
    int lane = rem & 63;
    int kbase = ks * 32 + (lane >> 4) * 8;
    int n     = nt * 16 + (lane & 15);
    short8 v;
#pragma unroll
    for (int j = 0; j < 8; ++j)
        v[j] = (short)f2bf(W[(kbase + j) * 256 + n]);
    *reinterpret_cast<short8*>(o + (((nt * 8) + ks) * 64 + lane) * 8) = v;
}

// ---------------- fused main kernel ----------------
template <bool BF16T>
__launch_bounds__(THREADS, 2)
__global__ void fused_kernel(const int* __restrict__ pv,
                             const int* __restrict__ qv,
                             const float* __restrict__ embf,
                             const unsigned short* __restrict__ embb,
                             const float* __restrict__ b1,
                             const float* __restrict__ b2,
                             const float* __restrict__ w3,
                             const float* __restrict__ b3,
                             const unsigned short* __restrict__ wpack,
                             float* __restrict__ out,
                             int M) {
    // A tile, reused as H tile after GEMM1. Row stride 512 B, XOR-swizzled
    // 16 B units (phys = u ^ (row & 31)) -> conflict-free ds_read_b128.
    __shared__ unsigned char lds_a[MT * 512];
    __shared__ float lds_part[4][MT];

    const int tid  = threadIdx.x;
    const int lane = tid & 63;
    const int wave = tid >> 6;              // 0..7
    const int base = blockIdx.x * MT;

    // ---- phase 0: gather + squared diff -> bf16 -> lds_a ----
    if (BF16T) {
        // 2 rows per iteration: lanes 0-31 row r, lanes 32-63 row r+1.
#pragma unroll
        for (int it = 0; it < 8; ++it) {
            int r  = wave * 16 + it * 2 + (lane >> 5);
            int gi = base + r;
            int pi = 0, qi = 0;
            if (gi < M) { pi = pv[gi]; qi = qv[gi]; }
            int c = lane & 31;                                  // 16 B unit in row
            uint4 a = *(reinterpret_cast<const uint4*>(embb + (size_t)pi * D) + c);
            uint4 b = *(reinterpret_cast<const uint4*>(embb + (size_t)qi * D) + c);
            uint4 o;
            o.x = sqdiff2(a.x, b.x);
            o.y = sqdiff2(a.y, b.y);
            o.z = sqdiff2(a.z, b.z);
            o.w = sqdiff2(a.w, b.w);
            unsigned int unit = (unsigned int)c ^ (unsigned int)(r & 31);
            *reinterpret_cast<uint4*>(&lds_a[(unsigned int)r * 512u + (unit << 4)]) = o;
        }
    } else {
        // fp32 fallback: 1 row per wave-iteration, 16 B/lane.
#pragma unroll
        for (int rr = 0; rr < 16; ++rr) {
            int r  = wave * 16 + rr;
            int gi = base + r;
            int pi = 0, qi = 0;
            if (gi < M) { pi = pv[gi]; qi = qv[gi]; }
            const float4* ep = reinterpret_cast<const float4*>(embf + (size_t)pi * D);
            const float4* eq = reinterpret_cast<const float4*>(embf + (size_t)qi * D);
            float4 a = ep[lane];
            float4 b = eq[lane];
            float d0 = a.x - b.x, d1 = a.y - b.y, d2 = a.z - b.z, d3 = a.w - b.w;
            unsigned int lo = (unsigned int)f2bf(d0 * d0) | ((unsigned int)f2bf(d1 * d1) << 16);
            unsigned int hi = (unsigned int)f2bf(d2 * d2) | ((unsigned int)f2bf(d3 * d3) << 16);
            unsigned int unit = (unsigned int)(lane >> 1) ^ (unsigned int)(r & 31);
            unsigned int addr = (unsigned int)r * 512u + (unit << 4) + (unsigned int)(lane & 1) * 8u;
            *reinterpret_cast<uint2*>(&lds_a[addr]) = make_uint2(lo, hi);
        }
    }
    __syncthreads();

    const int wm    = wave & 1;     // m half:    rows 64*wm .. +64
    const int wn    = wave >> 1;    // n quarter: cols 64*wn .. +64
    const int mbase = wm * 64;
    const int nbase = wn * 64;
    const int l15   = lane & 15;
    const int quad  = lane >> 4;

    const short8* wp1 = reinterpret_cast<const short8*>(wpack);
    const short8* wp2 = reinterpret_cast<const short8*>(wpack + 65536);

    f32x4 acc[4][4];
    short8 bfr[4][8];   // [ct][ks] register-resident B fragments

    // ================= GEMM1: h1 = relu(A @ W1 + b1) =================
#pragma unroll
    for (int ct = 0; ct < 4; ++ct) {
        int ntg = (nbase >> 4) + ct;
#pragma unroll
        for (int ks = 0; ks < 8; ++ks)
            bfr[ct][ks] = wp1[((ntg * 8) + ks) * 64 + lane];
    }
#pragma unroll
    for (int mt = 0; mt < 4; ++mt)
#pragma unroll
        for (int ct = 0; ct < 4; ++ct)
            acc[mt][ct] = (f32x4){0.f, 0.f, 0.f, 0.f};

#pragma unroll
    for (int ks = 0; ks < 8; ++ks) {
        short8 af[4];
#pragma unroll
        for (int mt = 0; mt < 4; ++mt) {
            int r = mbase + mt * 16 + l15;
            unsigned int unit = (unsigned int)(ks * 4 + quad) ^ (unsigned int)(r & 31);
            af[mt] = *reinterpret_cast<const short8*>(&lds_a[(unsigned int)r * 512u + (unit << 4)]);
        }
#pragma unroll
        for (int mt = 0; mt < 4; ++mt)
#pragma unroll
            for (int ct = 0; ct < 4; ++ct)
                acc[mt][ct] = __builtin_amdgcn_mfma_f32_16x16x32_bf16(
                    af[mt], bfr[ct][ks], acc[mt][ct], 0, 0, 0);
    }

    // A is dead; all waves must finish reading it before H overwrites it.
    __syncthreads();

    // epilogue 1: +b1, relu, bf16 -> lds_a (as H). C/D: col=lane&15, row=quad*4+reg
#pragma unroll
    for (int ct = 0; ct < 4; ++ct) {
        int c = nbase + ct * 16 + l15;
        float bias = b1[c];
#pragma unroll
        for (int mt = 0; mt < 4; ++mt) {
#pragma unroll
            for (int j = 0; j < 4; ++j) {
                float v = acc[mt][ct][j] + bias;
                v = fmaxf(v, 0.f);
                int r = mbase + mt * 16 + quad * 4 + j;
                unsigned int unit = (unsigned int)(c >> 3) ^ (unsigned int)(r & 31);
                unsigned int addr = (unsigned int)r * 512u + (unit << 4) + (unsigned int)(c & 7) * 2u;
                *reinterpret_cast<unsigned short*>(&lds_a[addr]) = f2bf(v);
            }
        }
    }
    __syncthreads();

    // ================= GEMM2: relu(H @ W2 + b2), fused w3 dot =================
#pragma unroll
    for (int ct = 0; ct < 4; ++ct) {
        int ntg = (nbase >> 4) + ct;
#pragma unroll
        for (int ks = 0; ks < 8; ++ks)
            bfr[ct][ks] = wp2[((ntg * 8) + ks) * 64 + lane];
    }
#pragma unroll
    for (int mt = 0; mt < 4; ++mt)
#pragma unroll
        for (int ct = 0; ct < 4; ++ct)
            acc[mt][ct] = (f32x4){0.f, 0.f, 0.f, 0.f};

#pragma unroll
    for (int ks = 0; ks < 8; ++ks) {
        short8 af[4];
#pragma unroll
        for (int mt = 0; mt < 4; ++mt) {
            int r = mbase + mt * 16 + l15;
            unsigned int unit = (unsigned int)(ks * 4 + quad) ^ (unsigned int)(r & 31);
            af[mt] = *reinterpret_cast<const short8*>(&lds_a[(unsigned int)r * 512u + (unit << 4)]);
        }
#pragma unroll
        for (int mt = 0; mt < 4; ++mt)
#pragma unroll
            for (int ct = 0; ct < 4; ++ct)
                acc[mt][ct] = __builtin_amdgcn_mfma_f32_16x16x32_bf16(
                    af[mt], bfr[ct][ks], acc[mt][ct], 0, 0, 0);
    }

    float part[4][4];
#pragma unroll
    for (int mt = 0; mt < 4; ++mt)
#pragma unroll
        for (int j = 0; j < 4; ++j)
            part[mt][j] = 0.f;

#pragma unroll
    for (int ct = 0; ct < 4; ++ct) {
        int c = nbase + ct * 16 + l15;
        float bias = b2[c];
        float w3v  = w3[c];
#pragma unroll
        for (int mt = 0; mt < 4; ++mt)
#pragma unroll
            for (int j = 0; j < 4; ++j) {
                float v = acc[mt][ct][j] + bias;
                v = fmaxf(v, 0.f);
                part[mt][j] += v * w3v;
            }
    }

    // reduce across the 16 lanes of each quad (same rows, different cols)
#pragma unroll
    for (int msk = 8; msk >= 1; msk >>= 1)
#pragma unroll
        for (int mt = 0; mt < 4; ++mt)
#pragma unroll
            for (int j = 0; j < 4; ++j)
                part[mt][j] += __shfl_xor(part[mt][j], msk, 64);

    if (l15 == 0) {
#pragma unroll
        for (int mt = 0; mt < 4; ++mt)
#pragma unroll
            for (int j = 0; j < 4; ++j) {
                int r = mbase + mt * 16 + quad * 4 + j;
                lds_part[wn][r] = part[mt][j];
            }
    }
    __syncthreads();

    if (tid < MT) {
        int gi = base + tid;
        if (gi < M) {
            float s = lds_part[0][tid] + lds_part[1][tid] +
                      lds_part[2][tid] + lds_part[3][tid] + b3[0];
            out[gi] = s;
        }
    }
}

extern "C" void kernel_launch(void* const* d_in, const int* in_sizes, int n_in,
                              void* d_out, int out_size, void* d_ws, size_t ws_size,
                              hipStream_t stream) {
    const int*   pv  = (const int*)d_in[0];
    const int*   qv  = (const int*)d_in[1];
    const float* emb = (const float*)d_in[2];
    const float* w1  = (const float*)d_in[3];
    const float* b1  = (const float*)d_in[4];
    const float* w2  = (const float*)d_in[5];
    const float* b2  = (const float*)d_in[6];
    const float* w3  = (const float*)d_in[7];
    const float* b3  = (const float*)d_in[8];
    float* out = (float*)d_out;
    const int M  = in_sizes[0];
    const int NV = in_sizes[2] / D;

    const size_t tbl_bytes   = (size_t)NV * D * sizeof(unsigned short); // 102.4 MB
    const size_t wpack_bytes = 2u * 65536u * sizeof(unsigned short);    // 256 KB
    const bool use_bf16 = (ws_size >= tbl_bytes + wpack_bytes);         // launch-constant

    unsigned short* table = (unsigned short*)d_ws;
    unsigned short* wpack = use_bf16
        ? (unsigned short*)((char*)d_ws + tbl_bytes)
        : (unsigned short*)d_ws;

    pack_w_kernel<<<32, 512, 0, stream>>>(w1, w2, wpack);

    int nblk = (M + MT - 1) / MT;
    if (use_bf16) {
        int nch = (int)((size_t)NV * D / 8);
        conv_emb_kernel<<<(nch + 255) / 256, 256, 0, stream>>>(emb, table, nch);
        fused_kernel<true><<<nblk, THREADS, 0, stream>>>(
            pv, qv, emb, table, b1, b2, w3, b3, wpack, out, M);
    } else {
        fused_kernel<false><<<nblk, THREADS, 0, stream>>>(
            pv, qv, emb, nullptr, b1, b2, w3, b3, wpack, out, M);
    }
}

// Round 3
// 513.692 us; speedup vs baseline: 1.2566x; 1.1749x over previous
//
#include <hip/hip_runtime.h>
#include <hip/hip_bf16.h>
#include <stdint.h>

// Fused gather + (ep-eq)^2 + MLP(256->256->256->1) for MI355X (gfx950).
//
// Round 3 changes vs round 2 (322 us, Occ 22%, MfmaUtil 17%, VGPR 92):
//  - VGPR 92 proved B-frags were NOT register-resident: compiler sank their
//    global loads into the K-loop -> L2-latency-bound MFMA loop. Now an
//    explicit depth-2 rotating register pipeline (bb0/bb1) prefetches B
//    fragments 2 k-steps ahead.
//  - Block shrunk to MT=64 / 256 threads (4 waves, 64x64 wave tile).
//    LDS 33 KB (A reused as H), launch_bounds(256,3) -> ~170 VGPR cap ->
//    3 blocks/CU = 12 waves/CU (was ~8). Cross-block overlap hides gather
//    and B-load latency under MFMA.

#define D 256
#define MT 64
#define THREADS 256

typedef __attribute__((ext_vector_type(8))) short short8;
typedef __attribute__((ext_vector_type(4))) float f32x4;

// bf16 round-to-nearest-even
__device__ __forceinline__ unsigned short f2bf(float f) {
    unsigned int u = __float_as_uint(f);
    unsigned int r = (u + 0x7FFFu + ((u >> 16) & 1u)) >> 16;
    return (unsigned short)r;
}
__device__ __forceinline__ float bflo(unsigned int u) { return __uint_as_float(u << 16); }
__device__ __forceinline__ float bfhi(unsigned int u) { return __uint_as_float(u & 0xFFFF0000u); }

__device__ __forceinline__ unsigned int sqdiff2(unsigned int p, unsigned int q) {
    float d0 = bflo(p) - bflo(q);
    float d1 = bfhi(p) - bfhi(q);
    return (unsigned int)f2bf(d0 * d0) | ((unsigned int)f2bf(d1 * d1) << 16);
}

// ---------------- embedding fp32 -> bf16 table ----------------
__global__ void conv_emb_kernel(const float* __restrict__ in,
                                unsigned short* __restrict__ out, int nchunks) {
    int i = blockIdx.x * blockDim.x + threadIdx.x;
    if (i >= nchunks) return;
    const float4* p = reinterpret_cast<const float4*>(in) + 2 * (size_t)i;
    float4 a = p[0], b = p[1];
    uint4 o;
    o.x = (unsigned int)f2bf(a.x) | ((unsigned int)f2bf(a.y) << 16);
    o.y = (unsigned int)f2bf(a.z) | ((unsigned int)f2bf(a.w) << 16);
    o.z = (unsigned int)f2bf(b.x) | ((unsigned int)f2bf(b.y) << 16);
    o.w = (unsigned int)f2bf(b.z) | ((unsigned int)f2bf(b.w) << 16);
    reinterpret_cast<uint4*>(out)[i] = o;
}

// ---------------- weight packing ----------------
// Pack W (row-major fp32 [K=256][N=256]) into bf16 B-fragments for
// v_mfma_f32_16x16x32_bf16. Fragment (nt, ks): lane L holds
//   B[k = ks*32 + (L>>4)*8 + j][n = nt*16 + (L&15)], j = 0..7
__global__ void pack_w_kernel(const float* __restrict__ w1,
                              const float* __restrict__ w2,
                              unsigned short* __restrict__ out) {
    int tid = blockIdx.x * blockDim.x + threadIdx.x;   // 0..16383
    int mat = tid >> 13;
    const float* W = mat ? w2 : w1;
    unsigned short* o = out + mat * 65536;
    int rem  = tid & 8191;
    int nt   = rem >> 9;
    int ks   = (rem >> 6) & 7;
    int lane = rem & 63;
    int kbase = ks * 32 + (lane >> 4) * 8;
    int n     = nt * 16 + (lane & 15);
    short8 v;
#pragma unroll
    for (int j = 0; j < 8; ++j)
        v[j] = (short)f2bf(W[(kbase + j) * 256 + n]);
    *reinterpret_cast<short8*>(o + (((nt * 8) + ks) * 64 + lane) * 8) = v;
}

// ---------------- fused main kernel ----------------
template <bool BF16T>
__launch_bounds__(THREADS, 3)
__global__ void fused_kernel(const int* __restrict__ pv,
                             const int* __restrict__ qv,
                             const float* __restrict__ embf,
                             const unsigned short* __restrict__ embb,
                             const float* __restrict__ b1,
                             const float* __restrict__ b2,
                             const float* __restrict__ w3,
                             const float* __restrict__ b3,
                             const unsigned short* __restrict__ wpack,
                             float* __restrict__ out,
                             int M) {
    // A tile (reused as H tile). Row stride 512 B, XOR-swizzled 16 B units
    // (phys = u ^ (row & 31)) -> conflict-free ds_read_b128 / writes.
    __shared__ unsigned char lds_a[MT * 512];
    __shared__ float lds_part[4][MT];

    const int tid  = threadIdx.x;
    const int lane = tid & 63;
    const int wave = tid >> 6;              // 0..3
    const int base = blockIdx.x * MT;

    // ---- phase 0: gather + squared diff -> bf16 -> lds_a ----
    if (BF16T) {
        // 2 rows per iteration: lanes 0-31 row r, lanes 32-63 row r+1.
#pragma unroll
        for (int it = 0; it < 8; ++it) {
            int r  = wave * 16 + it * 2 + (lane >> 5);
            int gi = base + r;
            int pi = 0, qi = 0;
            if (gi < M) { pi = pv[gi]; qi = qv[gi]; }
            int c = lane & 31;                                  // 16 B unit in row
            uint4 a = *(reinterpret_cast<const uint4*>(embb + (size_t)pi * D) + c);
            uint4 b = *(reinterpret_cast<const uint4*>(embb + (size_t)qi * D) + c);
            uint4 o;
            o.x = sqdiff2(a.x, b.x);
            o.y = sqdiff2(a.y, b.y);
            o.z = sqdiff2(a.z, b.z);
            o.w = sqdiff2(a.w, b.w);
            unsigned int unit = (unsigned int)c ^ (unsigned int)(r & 31);
            *reinterpret_cast<uint4*>(&lds_a[(unsigned int)r * 512u + (unit << 4)]) = o;
        }
    } else {
        // fp32 fallback: 1 row per wave-iteration, 16 B/lane.
#pragma unroll
        for (int rr = 0; rr < 16; ++rr) {
            int r  = wave * 16 + rr;
            int gi = base + r;
            int pi = 0, qi = 0;
            if (gi < M) { pi = pv[gi]; qi = qv[gi]; }
            const float4* ep = reinterpret_cast<const float4*>(embf + (size_t)pi * D);
            const float4* eq = reinterpret_cast<const float4*>(embf + (size_t)qi * D);
            float4 a = ep[lane];
            float4 b = eq[lane];
            float d0 = a.x - b.x, d1 = a.y - b.y, d2 = a.z - b.z, d3 = a.w - b.w;
            unsigned int lo = (unsigned int)f2bf(d0 * d0) | ((unsigned int)f2bf(d1 * d1) << 16);
            unsigned int hi = (unsigned int)f2bf(d2 * d2) | ((unsigned int)f2bf(d3 * d3) << 16);
            unsigned int unit = (unsigned int)(lane >> 1) ^ (unsigned int)(r & 31);
            unsigned int addr = (unsigned int)r * 512u + (unit << 4) + (unsigned int)(lane & 1) * 8u;
            *reinterpret_cast<uint2*>(&lds_a[addr]) = make_uint2(lo, hi);
        }
    }
    __syncthreads();

    const int wn    = wave;         // n quarter: cols 64*wn .. +64
    const int nbase = wn * 64;
    const int l15   = lane & 15;
    const int quad  = lane >> 4;

    const short8* wp1 = reinterpret_cast<const short8*>(wpack);
    const short8* wp2 = reinterpret_cast<const short8*>(wpack + 65536);

    f32x4 acc[4][4];
    // depth-2 rotating B-fragment pipeline (32 VGPRs)
    short8 bb0[4], bb1[4];

#define LOADB(buf, wp, ksv)                                            \
    _Pragma("unroll")                                                  \
    for (int ct = 0; ct < 4; ++ct)                                     \
        buf[ct] = (wp)[((((nbase >> 4) + ct) * 8) + (ksv)) * 64 + lane];

#define LOADA(af, ksv)                                                               \
    _Pragma("unroll")                                                                \
    for (int mt = 0; mt < 4; ++mt) {                                                 \
        int r = mt * 16 + l15;                                                       \
        unsigned int unit = (unsigned int)((ksv) * 4 + quad) ^ (unsigned int)(r & 31);\
        af[mt] = *reinterpret_cast<const short8*>(                                   \
            &lds_a[(unsigned int)r * 512u + (unit << 4)]);                           \
    }

#define MFMA16(bu)                                                      \
    _Pragma("unroll")                                                   \
    for (int mt = 0; mt < 4; ++mt)                                      \
        _Pragma("unroll")                                               \
        for (int ct = 0; ct < 4; ++ct)                                  \
            acc[mt][ct] = __builtin_amdgcn_mfma_f32_16x16x32_bf16(      \
                af[mt], bu[ct], acc[mt][ct], 0, 0, 0);

    // ================= GEMM1: h1 = relu(A @ W1 + b1) =================
#pragma unroll
    for (int mt = 0; mt < 4; ++mt)
#pragma unroll
        for (int ct = 0; ct < 4; ++ct)
            acc[mt][ct] = (f32x4){0.f, 0.f, 0.f, 0.f};

    LOADB(bb0, wp1, 0)
    LOADB(bb1, wp1, 1)
#pragma unroll
    for (int ks = 0; ks < 8; ++ks) {
        short8 af[4];
        LOADA(af, ks)
        if (ks & 1) {
            MFMA16(bb1)
            if (ks + 2 < 8) LOADB(bb1, wp1, ks + 2)
        } else {
            MFMA16(bb0)
            if (ks + 2 < 8) LOADB(bb0, wp1, ks + 2)
        }
    }

    // A is dead; all waves must finish reading it before H overwrites it.
    __syncthreads();

    // epilogue 1: +b1, relu, bf16 -> lds_a (as H). C/D: col=lane&15, row=quad*4+reg
#pragma unroll
    for (int ct = 0; ct < 4; ++ct) {
        int c = nbase + ct * 16 + l15;
        float bias = b1[c];
#pragma unroll
        for (int mt = 0; mt < 4; ++mt) {
#pragma unroll
            for (int j = 0; j < 4; ++j) {
                float v = acc[mt][ct][j] + bias;
                v = fmaxf(v, 0.f);
                int r = mt * 16 + quad * 4 + j;
                unsigned int unit = (unsigned int)(c >> 3) ^ (unsigned int)(r & 31);
                unsigned int addr = (unsigned int)r * 512u + (unit << 4) + (unsigned int)(c & 7) * 2u;
                *reinterpret_cast<unsigned short*>(&lds_a[addr]) = f2bf(v);
            }
        }
    }
    __syncthreads();

    // ================= GEMM2: relu(H @ W2 + b2), fused w3 dot =================
#pragma unroll
    for (int mt = 0; mt < 4; ++mt)
#pragma unroll
        for (int ct = 0; ct < 4; ++ct)
            acc[mt][ct] = (f32x4){0.f, 0.f, 0.f, 0.f};

    LOADB(bb0, wp2, 0)
    LOADB(bb1, wp2, 1)
#pragma unroll
    for (int ks = 0; ks < 8; ++ks) {
        short8 af[4];
        LOADA(af, ks)
        if (ks & 1) {
            MFMA16(bb1)
            if (ks + 2 < 8) LOADB(bb1, wp2, ks + 2)
        } else {
            MFMA16(bb0)
            if (ks + 2 < 8) LOADB(bb0, wp2, ks + 2)
        }
    }

    float part[4][4];
#pragma unroll
    for (int mt = 0; mt < 4; ++mt)
#pragma unroll
        for (int j = 0; j < 4; ++j)
            part[mt][j] = 0.f;

#pragma unroll
    for (int ct = 0; ct < 4; ++ct) {
        int c = nbase + ct * 16 + l15;
        float bias = b2[c];
        float w3v  = w3[c];
#pragma unroll
        for (int mt = 0; mt < 4; ++mt)
#pragma unroll
            for (int j = 0; j < 4; ++j) {
                float v = acc[mt][ct][j] + bias;
                v = fmaxf(v, 0.f);
                part[mt][j] += v * w3v;
            }
    }

    // reduce across the 16 lanes of each quad (same rows, different cols)
#pragma unroll
    for (int msk = 8; msk >= 1; msk >>= 1)
#pragma unroll
        for (int mt = 0; mt < 4; ++mt)
#pragma unroll
            for (int j = 0; j < 4; ++j)
                part[mt][j] += __shfl_xor(part[mt][j], msk, 64);

    if (l15 == 0) {
#pragma unroll
        for (int mt = 0; mt < 4; ++mt)
#pragma unroll
            for (int j = 0; j < 4; ++j) {
                int r = mt * 16 + quad * 4 + j;
                lds_part[wn][r] = part[mt][j];
            }
    }
    __syncthreads();

    if (tid < MT) {
        int gi = base + tid;
        if (gi < M) {
            float s = lds_part[0][tid] + lds_part[1][tid] +
                      lds_part[2][tid] + lds_part[3][tid] + b3[0];
            out[gi] = s;
        }
    }
}

extern "C" void kernel_launch(void* const* d_in, const int* in_sizes, int n_in,
                              void* d_out, int out_size, void* d_ws, size_t ws_size,
                              hipStream_t stream) {
    const int*   pv  = (const int*)d_in[0];
    const int*   qv  = (const int*)d_in[1];
    const float* emb = (const float*)d_in[2];
    const float* w1  = (const float*)d_in[3];
    const float* b1  = (const float*)d_in[4];
    const float* w2  = (const float*)d_in[5];
    const float* b2  = (const float*)d_in[6];
    const float* w3  = (const float*)d_in[7];
    const float* b3  = (const float*)d_in[8];
    float* out = (float*)d_out;
    const int M  = in_sizes[0];
    const int NV = in_sizes[2] / D;

    const size_t tbl_bytes   = (size_t)NV * D * sizeof(unsigned short); // 102.4 MB
    const size_t wpack_bytes = 2u * 65536u * sizeof(unsigned short);    // 256 KB
    const bool use_bf16 = (ws_size >= tbl_bytes + wpack_bytes);         // launch-constant

    unsigned short* table = (unsigned short*)d_ws;
    unsigned short* wpack = use_bf16
        ? (unsigned short*)((char*)d_ws + tbl_bytes)
        : (unsigned short*)d_ws;

    pack_w_kernel<<<32, 512, 0, stream>>>(w1, w2, wpack);

    int nblk = (M + MT - 1) / MT;
    if (use_bf16) {
        int nch = (int)((size_t)NV * D / 8);
        conv_emb_kernel<<<(nch + 255) / 256, 256, 0, stream>>>(emb, table, nch);
        fused_kernel<true><<<nblk, THREADS, 0, stream>>>(
            pv, qv, emb, table, b1, b2, w3, b3, wpack, out, M);
    } else {
        fused_kernel<false><<<nblk, THREADS, 0, stream>>>(
            pv, qv, emb, nullptr, b1, b2, w3, b3, wpack, out, M);
    }
}